// Round 1
// baseline (138.096 us; speedup 1.0000x reference)
//
#include <hip/hip_runtime.h>
#include <hip/hip_bf16.h>
#include <stdint.h>

// FullTucker: Z = U0 @ einsum('pqr,qb,rb->pb', G, U1^T@X1, U2^T@X2)
// D_OUT=D1=D2=512, R0=R1=R2=128, BATCH=8192. All f32 in/out; bf16 MFMA inside.

typedef __attribute__((ext_vector_type(8))) short bf8;   // 8 bf16 (4 VGPR)
typedef __attribute__((ext_vector_type(4))) short bf4;   // 4 bf16 (8B)
typedef __attribute__((ext_vector_type(4))) float f4;    // 4 f32

__device__ __forceinline__ unsigned short f2bf(float f){
  unsigned x = __builtin_bit_cast(unsigned, f);
  x += 0x7fffu + ((x >> 16) & 1u);            // RNE (inputs are finite)
  return (unsigned short)(x >> 16);
}
__device__ __forceinline__ float bf2f(unsigned short u){
  unsigned x = ((unsigned)u) << 16;
  return __builtin_bit_cast(float, x);
}
__device__ __forceinline__ void glds16(const void* g, void* l){
  __builtin_amdgcn_global_load_lds(
      (const __attribute__((address_space(1))) void*)g,
      (__attribute__((address_space(3))) void*)l, 16, 0, 0);
}

// ---------------- cast kernels ----------------
// G [128][128][128] f32 -> Gbf bf16 (same layout = G0 [128][16384]); U0 -> U0bf.
__global__ __launch_bounds__(256) void k_castG(const float* __restrict__ G,
                                               const float* __restrict__ U0,
                                               unsigned short* __restrict__ Gbf,
                                               unsigned short* __restrict__ U0bf){
  const int i4 = blockIdx.x * 256 + threadIdx.x;          // 0..540671
  const int NG4 = 2097152 / 4;
  const float4* src; unsigned short* dst; int j4;
  if (i4 < NG4){ src = (const float4*)G;  dst = Gbf;  j4 = i4; }
  else         { src = (const float4*)U0; dst = U0bf; j4 = i4 - NG4; }
  float4 v = src[j4];
  ushort4 o = make_ushort4(f2bf(v.x), f2bf(v.y), f2bf(v.z), f2bf(v.w));
  ((ushort4*)dst)[j4] = o;
}

// U1,U2 [512][128] f32 -> U1T,U2T [128][512] bf16 (transpose+cast; tiny arrays)
__global__ __launch_bounds__(256) void k_castUT(const float* __restrict__ U1,
                                                const float* __restrict__ U2,
                                                unsigned short* __restrict__ U1T,
                                                unsigned short* __restrict__ U2T){
  const int blk = blockIdx.x;                              // 0..31
  const float* U = (blk < 16) ? U1 : U2;
  unsigned short* UT = (blk < 16) ? U1T : U2T;
  const int d0 = (blk & 15) * 32;
  for (int r = 0; r < 16; ++r){
    int idx = r * 256 + threadIdx.x;                       // 32 d-rows x 128 q
    int d = d0 + (idx >> 7), q = idx & 127;
    UT[q * 512 + d] = f2bf(U[d * 128 + q]);
  }
}

// ---------------- UX GEMM: OUT[qr, b] = sum_d UT[qr][d] * X[d][b] ----------------
// M=128, N=8192 (BN=64 -> 128 blocks), K=512. 4 waves (2x2), wave tile 64x32.
// TRANS=false: write f32 [128][8192].  TRANS=true: write bf16 transposed [8192][128].
template<bool TRANS>
__global__ __launch_bounds__(256) void k_ux(const unsigned short* __restrict__ UT, // [128][512] bf16
                                            const float* __restrict__ X,           // [512][8192] f32
                                            float* __restrict__ OUTF,
                                            unsigned short* __restrict__ OUTT){
  __shared__ __align__(16) unsigned char lds[16384 + 8192]; // A 16KB + B 8KB
  unsigned char* ldsA = lds;
  unsigned char* ldsB = lds + 16384;
  const int tid = threadIdx.x, lane = tid & 63, wv = tid >> 6;
  const int wr = wv >> 1, wc = wv & 1;
  const int b0 = blockIdx.x * 64;
  f4 acc[4][2] = {};

  for (int it = 0; it < 8; ++it){
    const int k0 = it * 64;
    // A tile [128 q][64 d] bf16, swizzled via pre-swizzled global source
#pragma unroll
    for (int i = 0; i < 4; ++i){
      const int L = (wv * 4 + i) * 1024 + lane * 16;
      const int row = L >> 7;
      const int ss = (lane & 7) ^ (row & 7);
      glds16(UT + (size_t)row * 512 + k0 + ss * 8, ldsA + (wv * 4 + i) * 1024);
    }
    // B tile [64 b][64 d] bf16: gather 8 strided d per (b,slot), coalesced over b
#pragma unroll
    for (int c = 0; c < 2; ++c){
      const int slot = c * 4 + wv;            // 0..7
      const int bRow = lane;                  // 0..63
      bf8 v;
#pragma unroll
      for (int j = 0; j < 8; ++j)
        v[j] = (short)f2bf(X[(size_t)(k0 + slot * 8 + j) * 8192 + b0 + bRow]);
      *(bf8*)(ldsB + bRow * 128 + ((slot ^ (bRow & 7)) << 4)) = v;
    }
    __syncthreads();
#pragma unroll
    for (int kc = 0; kc < 2; ++kc){
      const int g = lane >> 4;
      bf8 a[4], b[2];
#pragma unroll
      for (int mf = 0; mf < 4; ++mf){
        const int r = wr * 64 + mf * 16 + (lane & 15);
        a[mf] = *(const bf8*)(ldsA + r * 128 + (((kc * 4 + g) ^ (r & 7)) << 4));
      }
#pragma unroll
      for (int nf = 0; nf < 2; ++nf){
        const int rb = wc * 32 + nf * 16 + (lane & 15);
        b[nf] = *(const bf8*)(ldsB + rb * 128 + (((kc * 4 + g) ^ (rb & 7)) << 4));
      }
#pragma unroll
      for (int mf = 0; mf < 4; ++mf)
#pragma unroll
        for (int nf = 0; nf < 2; ++nf)
          acc[mf][nf] = __builtin_amdgcn_mfma_f32_16x16x32_bf16(a[mf], b[nf], acc[mf][nf], 0, 0, 0);
    }
    __syncthreads();
  }

  if (!TRANS){
#pragma unroll
    for (int mf = 0; mf < 4; ++mf)
#pragma unroll
      for (int nf = 0; nf < 2; ++nf)
#pragma unroll
        for (int j = 0; j < 4; ++j){
          const int q = wr * 64 + mf * 16 + (lane >> 4) * 4 + j;
          const int b = b0 + wc * 32 + nf * 16 + (lane & 15);
          OUTF[(size_t)q * 8192 + b] = acc[mf][nf][j];
        }
  } else {
    // LDS bounce -> OUTT[b][r] bf16 coalesced. tbuf [64 b][128 r] swizzled.
#pragma unroll
    for (int mf = 0; mf < 4; ++mf)
#pragma unroll
      for (int nf = 0; nf < 2; ++nf){
        const int rBase = wr * 64 + mf * 16 + (lane >> 4) * 4;
        const int bL = wc * 32 + nf * 16 + (lane & 15);
        bf4 p;
#pragma unroll
        for (int j = 0; j < 4; ++j) p[j] = (short)f2bf(acc[mf][nf][j]);
        *(bf4*)(lds + ((bL * 256 + rBase * 2) ^ ((bL & 7) << 4))) = p;
      }
    __syncthreads();
#pragma unroll
    for (int u = 0; u < 4; ++u){
      const int sIdx = u * 256 + tid;         // 64 rows x 16 slots
      const int bL = sIdx >> 4, slot = sIdx & 15;
      bf8 v = *(const bf8*)(lds + bL * 256 + ((slot ^ (bL & 7)) << 4));
      *(bf8*)(OUTT + (size_t)(b0 + bL) * 128 + slot * 8) = v;
    }
  }
}

// ---------------- core GEMM with on-the-fly Khatri-Rao, split-K=4 ----------------
// core[p,b] = sum_k G0[p,k] * (UX1[q,b]*UX2[r,b]), k=q*128+r.
// Block: 128p x 128b, K-range 4096. Output PT[split][b][p] f32 (transposed epilogue).
__global__ __launch_bounds__(256) void k_core(const unsigned short* __restrict__ Gbf,  // [128][16384]
                                              const float* __restrict__ UX1,           // [128][8192] f32
                                              const unsigned short* __restrict__ UX2T, // [8192][128] bf16
                                              float* __restrict__ PT){                 // [4][8192][128] f32
  __shared__ __align__(16) unsigned char lds[32768];
  unsigned char* ldsA = lds;
  unsigned char* ldsB = lds + 16384;
  const int tid = threadIdx.x, lane = tid & 63, wv = tid >> 6;
  const int wr = wv >> 1, wc = wv & 1;
  const int b0 = blockIdx.x * 128;
  const int split = blockIdx.y;
  f4 acc[4][4] = {};

  for (int it = 0; it < 64; ++it){
    const int k0 = split * 4096 + it * 64;
    const int q = k0 >> 7;
    const int r0 = k0 & 127;
    // A tile: G rows, [128 p][64 k] bf16, glds with pre-swizzled source
#pragma unroll
    for (int i = 0; i < 4; ++i){
      const int L = (wv * 4 + i) * 1024 + lane * 16;
      const int row = L >> 7;
      const int ss = (lane & 7) ^ (row & 7);
      glds16(Gbf + (size_t)row * 16384 + k0 + ss * 8, ldsA + (wv * 4 + i) * 1024);
    }
    // B tile: KR^T [128 b][64 k] bf16 = UX2T chunk * UX1[q,b], swizzled ds_write
#pragma unroll
    for (int c = 0; c < 4; ++c){
      const int ci = c * 256 + tid;
      const int bRow = ci >> 3;
      const int slot = ci & 7;
      bf8 u2 = *(const bf8*)(UX2T + (size_t)(b0 + bRow) * 128 + r0 + slot * 8);
      const float x1 = UX1[(size_t)q * 8192 + b0 + bRow];
      bf8 v;
#pragma unroll
      for (int j = 0; j < 8; ++j)
        v[j] = (short)f2bf(bf2f((unsigned short)u2[j]) * x1);
      *(bf8*)(ldsB + bRow * 128 + ((slot ^ (bRow & 7)) << 4)) = v;
    }
    __syncthreads();
#pragma unroll
    for (int kc = 0; kc < 2; ++kc){
      const int g = lane >> 4;
      bf8 a[4], b[4];
#pragma unroll
      for (int mf = 0; mf < 4; ++mf){
        const int r = wr * 64 + mf * 16 + (lane & 15);
        a[mf] = *(const bf8*)(ldsA + r * 128 + (((kc * 4 + g) ^ (r & 7)) << 4));
      }
#pragma unroll
      for (int nf = 0; nf < 4; ++nf){
        const int rb = wc * 64 + nf * 16 + (lane & 15);
        b[nf] = *(const bf8*)(ldsB + rb * 128 + (((kc * 4 + g) ^ (rb & 7)) << 4));
      }
#pragma unroll
      for (int mf = 0; mf < 4; ++mf)
#pragma unroll
        for (int nf = 0; nf < 4; ++nf)
          acc[mf][nf] = __builtin_amdgcn_mfma_f32_16x16x32_bf16(a[mf], b[nf], acc[mf][nf], 0, 0, 0);
    }
    __syncthreads();
  }

  // epilogue: transpose acc -> PT[split][b][p], two 64-b halves through LDS (32KB f32)
  for (int h = 0; h < 2; ++h){
    if (wc == h){
#pragma unroll
      for (int mf = 0; mf < 4; ++mf)
#pragma unroll
        for (int nf = 0; nf < 4; ++nf){
          const int pq = (wr * 64 + mf * 16 + (lane >> 4) * 4) >> 2;  // p-quad 0..31
          const int bL = nf * 16 + (lane & 15);
          *(f4*)(lds + bL * 512 + ((pq ^ (bL & 7)) << 4)) = acc[mf][nf];
        }
    }
    __syncthreads();
#pragma unroll
    for (int u = 0; u < 8; ++u){
      const int sIdx = u * 256 + tid;        // 64 rows x 32 slots
      const int bL = sIdx >> 5, sl = sIdx & 31;
      f4 v = *(const f4*)(lds + bL * 512 + ((sl ^ (bL & 7)) << 4));
      *(f4*)(PT + (size_t)split * 1048576 + (size_t)(b0 + h * 64 + bL) * 128 + sl * 4) = v;
    }
    __syncthreads();
  }
}

// ---------------- reduce split-K partials -> coreT bf16 [8192][128] ----------------
__global__ __launch_bounds__(256) void k_red(const float* __restrict__ PT,
                                             unsigned short* __restrict__ coreT){
  const int i4 = blockIdx.x * 256 + threadIdx.x;           // 0..262143
  const f4* P = (const f4*)PT;
  f4 v = P[i4];
  v += P[262144 + i4];
  v += P[2 * 262144 + i4];
  v += P[3 * 262144 + i4];
  ushort4 o = make_ushort4(f2bf(v[0]), f2bf(v[1]), f2bf(v[2]), f2bf(v[3]));
  ((ushort4*)coreT)[i4] = o;
}

// ---------------- Z = U0 @ core: M=512, N=8192, K=128 ----------------
__global__ __launch_bounds__(256) void k_z(const unsigned short* __restrict__ U0bf,  // [512][128] bf16
                                           const unsigned short* __restrict__ coreT, // [8192][128] bf16
                                           float* __restrict__ Z){                   // [512][8192] f32
  __shared__ __align__(16) unsigned char lds[32768];
  unsigned char* ldsA = lds;
  unsigned char* ldsB = lds + 16384;
  const int tid = threadIdx.x, lane = tid & 63, wv = tid >> 6;
  const int wr = wv >> 1, wc = wv & 1;
  const int b0 = blockIdx.x * 128;
  const int d0 = blockIdx.y * 128;
  f4 acc[4][4] = {};

#pragma unroll
  for (int it = 0; it < 2; ++it){
    const int k0 = it * 64;
#pragma unroll
    for (int i = 0; i < 4; ++i){
      const int L = (wv * 4 + i) * 1024 + lane * 16;
      const int row = L >> 7;
      const int ss = (lane & 7) ^ (row & 7);
      glds16(U0bf + (size_t)(d0 + row) * 128 + k0 + ss * 8, ldsA + (wv * 4 + i) * 1024);
      glds16(coreT + (size_t)(b0 + row) * 128 + k0 + ss * 8, ldsB + (wv * 4 + i) * 1024);
    }
    __syncthreads();
#pragma unroll
    for (int kc = 0; kc < 2; ++kc){
      const int g = lane >> 4;
      bf8 a[4], b[4];
#pragma unroll
      for (int mf = 0; mf < 4; ++mf){
        const int r = wr * 64 + mf * 16 + (lane & 15);
        a[mf] = *(const bf8*)(ldsA + r * 128 + (((kc * 4 + g) ^ (r & 7)) << 4));
      }
#pragma unroll
      for (int nf = 0; nf < 4; ++nf){
        const int rb = wc * 64 + nf * 16 + (lane & 15);
        b[nf] = *(const bf8*)(ldsB + rb * 128 + (((kc * 4 + g) ^ (rb & 7)) << 4));
      }
#pragma unroll
      for (int mf = 0; mf < 4; ++mf)
#pragma unroll
        for (int nf = 0; nf < 4; ++nf)
          acc[mf][nf] = __builtin_amdgcn_mfma_f32_16x16x32_bf16(a[mf], b[nf], acc[mf][nf], 0, 0, 0);
    }
    __syncthreads();
  }
#pragma unroll
  for (int mf = 0; mf < 4; ++mf)
#pragma unroll
    for (int nf = 0; nf < 4; ++nf)
#pragma unroll
      for (int j = 0; j < 4; ++j){
        const int d = d0 + wr * 64 + mf * 16 + (lane >> 4) * 4 + j;
        const int b = b0 + wc * 64 + nf * 16 + (lane & 15);
        Z[(size_t)d * 8192 + b] = acc[mf][nf][j];
      }
}

// ---------------- host launch ----------------
extern "C" void kernel_launch(void* const* d_in, const int* in_sizes, int n_in,
                              void* d_out, int out_size, void* d_ws, size_t ws_size,
                              hipStream_t stream){
  const float* X1 = (const float*)d_in[0];   // [512][8192]
  const float* X2 = (const float*)d_in[1];   // [512][8192]
  const float* U0 = (const float*)d_in[2];   // [512][128]
  const float* U1 = (const float*)d_in[3];   // [512][128]
  const float* U2 = (const float*)d_in[4];   // [512][128]
  const float* G  = (const float*)d_in[5];   // [128][128][128]
  float* Z = (float*)d_out;                  // [512][8192]

  char* ws = (char*)d_ws;
  unsigned short* Gbf   = (unsigned short*)(ws);              //  4,194,304 B
  unsigned short* U0bf  = (unsigned short*)(ws + 4194304);    //    131,072 B
  unsigned short* U1T   = (unsigned short*)(ws + 4325376);    //    131,072 B
  unsigned short* U2T   = (unsigned short*)(ws + 4456448);    //    131,072 B
  float*          UX1   = (float*)         (ws + 4587520);    //  4,194,304 B
  unsigned short* UX2T  = (unsigned short*)(ws + 8781824);    //  2,097,152 B
  unsigned short* coreT = (unsigned short*)(ws + 10878976);   //  2,097,152 B
  float*          PT    = (float*)         (ws + 12976128);   // 16,777,216 B
  // total 29,753,344 B

  k_castG <<<dim3(2112), dim3(256), 0, stream>>>(G, U0, Gbf, U0bf);
  k_castUT<<<dim3(32),   dim3(256), 0, stream>>>(U1, U2, U1T, U2T);
  k_ux<false><<<dim3(128), dim3(256), 0, stream>>>(U1T, X1, UX1, (unsigned short*)nullptr);
  k_ux<true> <<<dim3(128), dim3(256), 0, stream>>>(U2T, X2, (float*)nullptr, UX2T);
  k_core  <<<dim3(64, 4), dim3(256), 0, stream>>>(Gbf, UX1, UX2T, PT);
  k_red   <<<dim3(1024),  dim3(256), 0, stream>>>(PT, coreT);
  k_z     <<<dim3(64, 4), dim3(256), 0, stream>>>(U0bf, coreT, Z);
}

// Round 2
// 71.730 us; speedup vs baseline: 1.9252x; 1.9252x over previous
//
#include <hip/hip_runtime.h>
#include <hip/hip_bf16.h>
#include <stdint.h>

// FullTucker: Z = U0 @ einsum('pqr,qb,rb->pb', G, U1^T@X1, U2^T@X2)
// D_OUT=D1=D2=512, R0=R1=R2=128, BATCH=8192. f32 in/out; bf16 MFMA inside.
// k_core reassociated: core[p,b] = sum_q x1[q,b] * (sum_r G[p,q,r]*u2[r,b])
//   -> per-q plain GEMM with B (UX2T) staged once + B-frags hoisted in regs,
//      G streamed via double-buffered global_load_lds, x1 applied as f32 fmac.

typedef __attribute__((ext_vector_type(8))) short bf8;   // 8 bf16 (4 VGPR)
typedef __attribute__((ext_vector_type(4))) short bf4;   // 4 bf16 (8B)
typedef __attribute__((ext_vector_type(4))) float f4;    // 4 f32

__device__ __forceinline__ unsigned short f2bf(float f){
  unsigned x = __builtin_bit_cast(unsigned, f);
  x += 0x7fffu + ((x >> 16) & 1u);            // RNE (inputs finite)
  return (unsigned short)(x >> 16);
}
__device__ __forceinline__ float bf2f(unsigned short u){
  unsigned x = ((unsigned)u) << 16;
  return __builtin_bit_cast(float, x);
}
__device__ __forceinline__ void glds16(const void* g, void* l){
  __builtin_amdgcn_global_load_lds(
      (const __attribute__((address_space(1))) void*)g,
      (__attribute__((address_space(3))) void*)l, 16, 0, 0);
}

// ---------------- cast kernels ----------------
__global__ __launch_bounds__(256) void k_castG(const float* __restrict__ G,
                                               const float* __restrict__ U0,
                                               unsigned short* __restrict__ Gbf,
                                               unsigned short* __restrict__ U0bf){
  const int i4 = blockIdx.x * 256 + threadIdx.x;          // 0..540671
  const int NG4 = 2097152 / 4;
  const float4* src; unsigned short* dst; int j4;
  if (i4 < NG4){ src = (const float4*)G;  dst = Gbf;  j4 = i4; }
  else         { src = (const float4*)U0; dst = U0bf; j4 = i4 - NG4; }
  float4 v = src[j4];
  ushort4 o = make_ushort4(f2bf(v.x), f2bf(v.y), f2bf(v.z), f2bf(v.w));
  ((ushort4*)dst)[j4] = o;
}

// U1,U2 [512][128] f32 -> U1T,U2T [128][512] bf16 (transpose+cast)
__global__ __launch_bounds__(256) void k_castUT(const float* __restrict__ U1,
                                                const float* __restrict__ U2,
                                                unsigned short* __restrict__ U1T,
                                                unsigned short* __restrict__ U2T){
  const int blk = blockIdx.x;                              // 0..511
  const float* U = (blk < 256) ? U1 : U2;
  unsigned short* UT = (blk < 256) ? U1T : U2T;
  const int idx = (blk & 255) * 256 + threadIdx.x;         // 0..65535
  const int d = idx >> 7, q = idx & 127;
  UT[q * 512 + d] = f2bf(U[idx]);
}

// ---------------- UX GEMM (both modes, one dispatch) ----------------
// OUT[qr,b] = sum_d UT[qr][d]*X[d][b]. blockIdx.y==0: f32 out; ==1: bf16 transposed.
__global__ __launch_bounds__(256) void k_ux2(const unsigned short* __restrict__ U1T,
                                             const unsigned short* __restrict__ U2T,
                                             const float* __restrict__ X1,
                                             const float* __restrict__ X2,
                                             float* __restrict__ OUTF,
                                             unsigned short* __restrict__ OUTT){
  const bool second = (blockIdx.y != 0);
  const unsigned short* UT = second ? U2T : U1T;
  const float* X = second ? X2 : X1;
  __shared__ __align__(16) unsigned char lds[16384 + 8192];
  unsigned char* ldsA = lds;
  unsigned char* ldsB = lds + 16384;
  const int tid = threadIdx.x, lane = tid & 63, wv = tid >> 6;
  const int wr = wv >> 1, wc = wv & 1;
  const int b0 = blockIdx.x * 64;
  f4 acc[4][2] = {};

  for (int it = 0; it < 8; ++it){
    const int k0 = it * 64;
#pragma unroll
    for (int i = 0; i < 4; ++i){
      const int L = (wv * 4 + i) * 1024 + lane * 16;
      const int row = L >> 7;
      const int ss = (lane & 7) ^ (row & 7);
      glds16(UT + (size_t)row * 512 + k0 + ss * 8, ldsA + (wv * 4 + i) * 1024);
    }
#pragma unroll
    for (int c = 0; c < 2; ++c){
      const int slot = c * 4 + wv;
      const int bRow = lane;
      bf8 v;
#pragma unroll
      for (int j = 0; j < 8; ++j)
        v[j] = (short)f2bf(X[(size_t)(k0 + slot * 8 + j) * 8192 + b0 + bRow]);
      *(bf8*)(ldsB + bRow * 128 + ((slot ^ (bRow & 7)) << 4)) = v;
    }
    __syncthreads();
#pragma unroll
    for (int kc = 0; kc < 2; ++kc){
      const int g = lane >> 4;
      bf8 a[4], b[2];
#pragma unroll
      for (int mf = 0; mf < 4; ++mf){
        const int r = wr * 64 + mf * 16 + (lane & 15);
        a[mf] = *(const bf8*)(ldsA + r * 128 + (((kc * 4 + g) ^ (r & 7)) << 4));
      }
#pragma unroll
      for (int nf = 0; nf < 2; ++nf){
        const int rb = wc * 32 + nf * 16 + (lane & 15);
        b[nf] = *(const bf8*)(ldsB + rb * 128 + (((kc * 4 + g) ^ (rb & 7)) << 4));
      }
#pragma unroll
      for (int mf = 0; mf < 4; ++mf)
#pragma unroll
        for (int nf = 0; nf < 2; ++nf)
          acc[mf][nf] = __builtin_amdgcn_mfma_f32_16x16x32_bf16(a[mf], b[nf], acc[mf][nf], 0, 0, 0);
    }
    __syncthreads();
  }

  if (!second){
#pragma unroll
    for (int mf = 0; mf < 4; ++mf)
#pragma unroll
      for (int nf = 0; nf < 2; ++nf)
#pragma unroll
        for (int j = 0; j < 4; ++j){
          const int q = wr * 64 + mf * 16 + (lane >> 4) * 4 + j;
          const int b = b0 + wc * 32 + nf * 16 + (lane & 15);
          OUTF[(size_t)q * 8192 + b] = acc[mf][nf][j];
        }
  } else {
#pragma unroll
    for (int mf = 0; mf < 4; ++mf)
#pragma unroll
      for (int nf = 0; nf < 2; ++nf){
        const int rBase = wr * 64 + mf * 16 + (lane >> 4) * 4;
        const int bL = wc * 32 + nf * 16 + (lane & 15);
        bf4 p;
#pragma unroll
        for (int j = 0; j < 4; ++j) p[j] = (short)f2bf(acc[mf][nf][j]);
        *(bf4*)(lds + ((bL * 256 + rBase * 2) ^ ((bL & 7) << 4))) = p;
      }
    __syncthreads();
#pragma unroll
    for (int u = 0; u < 4; ++u){
      const int sIdx = u * 256 + tid;
      const int bL = sIdx >> 4, slot = sIdx & 15;
      bf8 v = *(const bf8*)(lds + bL * 256 + ((slot ^ (bL & 7)) << 4));
      *(bf8*)(OUTT + (size_t)(b0 + bL) * 128 + slot * 8) = v;
    }
  }
}

// ---------------- core: per-q GEMM + f32 fmac fold of UX1, split-K(q)=4 ----------------
// Block: 128p x 128b, 8 waves (2x4), wave 64p x 32b. q-range: 32 per split.
// LDS: A dbuf 2x32KB (2 halves [128p][64r]) + B 32KB (2 halves [128b][64r]).
__global__ __launch_bounds__(512, 2) void k_core(const unsigned short* __restrict__ Gbf,  // [128][16384]
                                                 const float* __restrict__ UX1,           // [128][8192]
                                                 const unsigned short* __restrict__ UX2T, // [8192][128]
                                                 float* __restrict__ PT){                 // [4][8192][128]
  __shared__ __align__(16) unsigned char lds[98304];
  unsigned char* ldsB = lds + 65536;
  const int tid = threadIdx.x, lane = tid & 63, wv = tid >> 6;
  const int wr = wv >> 2, wc = wv & 3;        // 2 x 4 waves
  const int b0 = blockIdx.x * 128;
  const int split = blockIdx.y;               // q in [split*32, split*32+32)
  const int g = lane >> 4, l15 = lane & 15;

  // stage B (UX2T rows b0..b0+127, all 128 r) once: two halves [128b][64r]
#pragma unroll
  for (int h = 0; h < 2; ++h)
#pragma unroll
    for (int rnd = 0; rnd < 2; ++rnd){
      const int off = rnd * 8192 + wv * 1024 + lane * 16;
      const int row = off >> 7;               // b-row 0..127
      const int ss = (lane & 7) ^ (row & 7);
      glds16(UX2T + (size_t)(b0 + row) * 128 + h * 64 + ss * 8,
             ldsB + h * 16384 + off);
    }

  const int q0 = split * 32;
  // stage A(q0) into buf 0: G slice [128p][128r], two halves [128p][64r]
#pragma unroll
  for (int h = 0; h < 2; ++h)
#pragma unroll
    for (int rnd = 0; rnd < 2; ++rnd){
      const int off = rnd * 8192 + wv * 1024 + lane * 16;
      const int row = off >> 7;               // p-row
      const int ss = (lane & 7) ^ (row & 7);
      glds16(Gbf + (size_t)row * 16384 + q0 * 128 + h * 64 + ss * 8,
             lds + h * 16384 + off);
    }
  __syncthreads();

  // hoist B fragments for the whole kernel: [kc][nf], 8 x bf8
  bf8 bfr[4][2];
#pragma unroll
  for (int kc = 0; kc < 4; ++kc)
#pragma unroll
    for (int nf = 0; nf < 2; ++nf){
      const int rb = wc * 32 + nf * 16 + l15;
      bfr[kc][nf] = *(const bf8*)(ldsB + (kc >> 1) * 16384 + rb * 128 +
                                  ((((kc & 1) * 4 + g) ^ (rb & 7)) << 4));
    }

  f4 acc[4][2] = {};
  int buf = 0;
  for (int i = 0; i < 32; ++i){
    const int q = q0 + i;
    if (i + 1 < 32){
#pragma unroll
      for (int h = 0; h < 2; ++h)
#pragma unroll
        for (int rnd = 0; rnd < 2; ++rnd){
          const int off = rnd * 8192 + wv * 1024 + lane * 16;
          const int row = off >> 7;
          const int ss = (lane & 7) ^ (row & 7);
          glds16(Gbf + (size_t)row * 16384 + (q + 1) * 128 + h * 64 + ss * 8,
                 lds + (buf ^ 1) * 32768 + h * 16384 + off);
        }
    }
    float x1v[2];
#pragma unroll
    for (int nf = 0; nf < 2; ++nf)
      x1v[nf] = UX1[(size_t)q * 8192 + b0 + wc * 32 + nf * 16 + l15];

    const unsigned char* A = lds + buf * 32768;
    f4 y[4][2];
#pragma unroll
    for (int kc = 0; kc < 4; ++kc){
      bf8 a[4];
#pragma unroll
      for (int mf = 0; mf < 4; ++mf){
        const int r = wr * 64 + mf * 16 + l15;
        a[mf] = *(const bf8*)(A + (kc >> 1) * 16384 + r * 128 +
                              ((((kc & 1) * 4 + g) ^ (r & 7)) << 4));
      }
#pragma unroll
      for (int mf = 0; mf < 4; ++mf)
#pragma unroll
        for (int nf = 0; nf < 2; ++nf){
          f4 c = (kc == 0) ? (f4){0.f, 0.f, 0.f, 0.f} : y[mf][nf];
          y[mf][nf] = __builtin_amdgcn_mfma_f32_16x16x32_bf16(a[mf], bfr[kc][nf], c, 0, 0, 0);
        }
    }
#pragma unroll
    for (int mf = 0; mf < 4; ++mf)
#pragma unroll
      for (int nf = 0; nf < 2; ++nf)
        acc[mf][nf] += y[mf][nf] * x1v[nf];
    __syncthreads();                           // drains glds(q+1) + buf handoff
    buf ^= 1;
  }

  // epilogue: acc -> PT[split][b][p] via LDS transpose (64KB region, swizzled)
#pragma unroll
  for (int mf = 0; mf < 4; ++mf)
#pragma unroll
    for (int nf = 0; nf < 2; ++nf){
      const int pq = wr * 16 + mf * 4 + g;     // p>>2, 0..31
      const int bL = wc * 32 + nf * 16 + l15;  // 0..127
      *(f4*)(lds + bL * 512 + ((pq ^ (bL & 7)) << 4)) = acc[mf][nf];
    }
  __syncthreads();
#pragma unroll
  for (int rnd = 0; rnd < 8; ++rnd){
    const int idx = rnd * 512 + tid;           // over 4096 f4
    const int bL = idx >> 5, sl = idx & 31;
    f4 v = *(const f4*)(lds + bL * 512 + ((sl ^ (bL & 7)) << 4));
    *(f4*)(PT + (size_t)split * 1048576 + (size_t)(b0 + bL) * 128 + sl * 4) = v;
  }
}

// ---------------- reduce split-K partials -> coreT bf16 [8192][128] ----------------
__global__ __launch_bounds__(256) void k_red(const float* __restrict__ PT,
                                             unsigned short* __restrict__ coreT){
  const int i4 = blockIdx.x * 256 + threadIdx.x;           // 0..262143
  const f4* P = (const f4*)PT;
  f4 v = P[i4];
  v += P[262144 + i4];
  v += P[2 * 262144 + i4];
  v += P[3 * 262144 + i4];
  ushort4 o = make_ushort4(f2bf(v[0]), f2bf(v[1]), f2bf(v[2]), f2bf(v[3]));
  ((ushort4*)coreT)[i4] = o;
}

// ---------------- Z = U0 @ core: M=512, N=8192, K=128 ----------------
__global__ __launch_bounds__(256) void k_z(const unsigned short* __restrict__ U0bf,  // [512][128]
                                           const unsigned short* __restrict__ coreT, // [8192][128]
                                           float* __restrict__ Z){                   // [512][8192]
  __shared__ __align__(16) unsigned char lds[32768];
  unsigned char* ldsA = lds;
  unsigned char* ldsB = lds + 16384;
  const int tid = threadIdx.x, lane = tid & 63, wv = tid >> 6;
  const int wr = wv >> 1, wc = wv & 1;
  const int b0 = blockIdx.x * 128;
  const int d0 = blockIdx.y * 128;
  f4 acc[4][4] = {};

#pragma unroll
  for (int it = 0; it < 2; ++it){
    const int k0 = it * 64;
#pragma unroll
    for (int i = 0; i < 4; ++i){
      const int L = (wv * 4 + i) * 1024 + lane * 16;
      const int row = L >> 7;
      const int ss = (lane & 7) ^ (row & 7);
      glds16(U0bf + (size_t)(d0 + row) * 128 + k0 + ss * 8, ldsA + (wv * 4 + i) * 1024);
      glds16(coreT + (size_t)(b0 + row) * 128 + k0 + ss * 8, ldsB + (wv * 4 + i) * 1024);
    }
    __syncthreads();
#pragma unroll
    for (int kc = 0; kc < 2; ++kc){
      const int g = lane >> 4;
      bf8 a[4], b[4];
#pragma unroll
      for (int mf = 0; mf < 4; ++mf){
        const int r = wr * 64 + mf * 16 + (lane & 15);
        a[mf] = *(const bf8*)(ldsA + r * 128 + (((kc * 4 + g) ^ (r & 7)) << 4));
      }
#pragma unroll
      for (int nf = 0; nf < 4; ++nf){
        const int rb = wc * 64 + nf * 16 + (lane & 15);
        b[nf] = *(const bf8*)(ldsB + rb * 128 + (((kc * 4 + g) ^ (rb & 7)) << 4));
      }
#pragma unroll
      for (int mf = 0; mf < 4; ++mf)
#pragma unroll
        for (int nf = 0; nf < 4; ++nf)
          acc[mf][nf] = __builtin_amdgcn_mfma_f32_16x16x32_bf16(a[mf], b[nf], acc[mf][nf], 0, 0, 0);
    }
    __syncthreads();
  }
#pragma unroll
  for (int mf = 0; mf < 4; ++mf)
#pragma unroll
    for (int nf = 0; nf < 4; ++nf)
#pragma unroll
      for (int j = 0; j < 4; ++j){
        const int d = d0 + wr * 64 + mf * 16 + (lane >> 4) * 4 + j;
        const int b = b0 + wc * 64 + nf * 16 + (lane & 15);
        Z[(size_t)d * 8192 + b] = acc[mf][nf][j];
      }
}

// ---------------- host launch ----------------
extern "C" void kernel_launch(void* const* d_in, const int* in_sizes, int n_in,
                              void* d_out, int out_size, void* d_ws, size_t ws_size,
                              hipStream_t stream){
  const float* X1 = (const float*)d_in[0];
  const float* X2 = (const float*)d_in[1];
  const float* U0 = (const float*)d_in[2];
  const float* U1 = (const float*)d_in[3];
  const float* U2 = (const float*)d_in[4];
  const float* G  = (const float*)d_in[5];
  float* Z = (float*)d_out;

  char* ws = (char*)d_ws;
  unsigned short* Gbf   = (unsigned short*)(ws);              //  4,194,304 B
  unsigned short* U0bf  = (unsigned short*)(ws + 4194304);    //    131,072 B
  unsigned short* U1T   = (unsigned short*)(ws + 4325376);    //    131,072 B
  unsigned short* U2T   = (unsigned short*)(ws + 4456448);    //    131,072 B
  float*          UX1   = (float*)         (ws + 4587520);    //  4,194,304 B
  unsigned short* UX2T  = (unsigned short*)(ws + 8781824);    //  2,097,152 B
  unsigned short* coreT = (unsigned short*)(ws + 10878976);   //  2,097,152 B
  float*          PT    = (float*)         (ws + 12976128);   // 16,777,216 B

  k_castG <<<dim3(2112), dim3(256), 0, stream>>>(G, U0, Gbf, U0bf);
  k_castUT<<<dim3(512),  dim3(256), 0, stream>>>(U1, U2, U1T, U2T);
  k_ux2   <<<dim3(128, 2), dim3(256), 0, stream>>>(U1T, U2T, X1, X2, UX1, UX2T);
  k_core  <<<dim3(64, 4), dim3(512), 0, stream>>>(Gbf, UX1, UX2T, PT);
  k_red   <<<dim3(1024),  dim3(256), 0, stream>>>(PT, coreT);
  k_z     <<<dim3(64, 4), dim3(256), 0, stream>>>(U0bf, coreT, Z);
}